// Round 9
// baseline (1610.135 us; speedup 1.0000x reference)
//
#include <hip/hip_runtime.h>
#include <hip/hip_bf16.h>
#include <cstdint>
#include <cstddef>

// Problem dims (fixed)
#define E_     16
#define H_     1024
#define D_     1024
#define T_     2048
#define TWO_D  2048
#define KFLAT  (E_ * D_)   // 16384

typedef float  f32x4  __attribute__((ext_vector_type(4)));
typedef short  bf16x8 __attribute__((ext_vector_type(8)));

static __device__ __forceinline__ unsigned short f2bf(float f) {
  union { float f; unsigned u; } v; v.f = f;
  unsigned u = v.u;
  unsigned r = (u + 0x7FFFu + ((u >> 16) & 1u)) >> 16;   // RNE
  return (unsigned short)r;
}

static __device__ __forceinline__ void gload16(const void* g, void* l) {
  __builtin_amdgcn_global_load_lds(
      (const __attribute__((address_space(1))) void*)g,
      (__attribute__((address_space(3))) void*)l, 16, 0, 0);
}

// ---------------------------------------------------------------------------
// T1: gate_up_proj [E][H][2D] f32 -> Wg^T [E][D][H] bf16, Wu^T [E][D][H] bf16
//   float4 reads (16B/lane), LDS f32 tile (pad 130 -> b64-aligned rows),
//   ushort4 writes (8B/lane, 128B contiguous per 16 lanes).
// grid (TWO_D/128=16, H/64=16, E=16), 256 threads
__global__ void k_trans_gu(const float* __restrict__ gu,
                           unsigned short* __restrict__ wg,
                           unsigned short* __restrict__ wu) {
  __shared__ float tile[64][130];          // 520B row stride (8B-aligned)
  const int e  = blockIdx.z;
  const int h0 = blockIdx.y * 64;
  const int c0 = blockIdx.x * 128;
  const int tid = threadIdx.x;
  const float* src = gu + (size_t)e * H_ * TWO_D;
#pragma unroll
  for (int i = 0; i < 8; ++i) {            // 2048 float4 items
    int item = tid + i * 256;
    int row = item >> 5, fc = item & 31;
    float4 v = *(const float4*)&src[(size_t)(h0 + row) * TWO_D + c0 + fc * 4];
    *(float2*)&tile[row][fc * 4]     = make_float2(v.x, v.y);
    *(float2*)&tile[row][fc * 4 + 2] = make_float2(v.z, v.w);
  }
  __syncthreads();
  const int d0 = c0 >> 1;                  // 64 d per block
#pragma unroll
  for (int i = 0; i < 4; ++i) {            // 1024 items: (dg, h-quad)
    int item = tid + i * 256;
    int dg = item >> 4, hq = item & 15;
    const int c = dg * 2;
    ushort4 og, ou;
    og.x = f2bf(tile[hq * 4 + 0][c]);     og.y = f2bf(tile[hq * 4 + 1][c]);
    og.z = f2bf(tile[hq * 4 + 2][c]);     og.w = f2bf(tile[hq * 4 + 3][c]);
    ou.x = f2bf(tile[hq * 4 + 0][c + 1]); ou.y = f2bf(tile[hq * 4 + 1][c + 1]);
    ou.z = f2bf(tile[hq * 4 + 2][c + 1]); ou.w = f2bf(tile[hq * 4 + 3][c + 1]);
    const size_t o = (((size_t)e << 10) + d0 + dg) * H_ + h0 + hq * 4;
    *(ushort4*)&wg[o] = og;
    *(ushort4*)&wu[o] = ou;
  }
}

// ---------------------------------------------------------------------------
// T2: down_proj [E][D][H] f32 -> Wd^T [H][E*D] bf16
//   float4 reads, LDS pad 66, ushort4 writes (256B contiguous per 32 lanes).
// grid (H/64=16, D/128=8, E=16), 256 threads
__global__ void k_trans_dn(const float* __restrict__ dn,
                           unsigned short* __restrict__ wd) {
  __shared__ float tile[128][66];          // 264B row stride (8B-aligned)
  const int e  = blockIdx.z;
  const int d0 = blockIdx.y * 128;
  const int h0 = blockIdx.x * 64;
  const int tid = threadIdx.x;
  const float* src = dn + (size_t)e * D_ * H_;
#pragma unroll
  for (int i = 0; i < 8; ++i) {            // 2048 float4 items
    int item = tid + i * 256;
    int row = item >> 4, fc = item & 15;
    float4 v = *(const float4*)&src[(size_t)(d0 + row) * H_ + h0 + fc * 4];
    *(float2*)&tile[row][fc * 4]     = make_float2(v.x, v.y);
    *(float2*)&tile[row][fc * 4 + 2] = make_float2(v.z, v.w);
  }
  __syncthreads();
#pragma unroll
  for (int i = 0; i < 8; ++i) {            // 2048 items: (hr, d-quad)
    int item = tid + i * 256;
    int hr = item >> 5, dq = item & 31;
    ushort4 o;
    o.x = f2bf(tile[dq * 4 + 0][hr]); o.y = f2bf(tile[dq * 4 + 1][hr]);
    o.z = f2bf(tile[dq * 4 + 2][hr]); o.w = f2bf(tile[dq * 4 + 3][hr]);
    *(ushort4*)&wd[(size_t)(h0 + hr) * KFLAT + (e << 10) + d0 + dq * 4] = o;
  }
}

// ---------------------------------------------------------------------------
// T3: hidden_states f32 -> bf16
__global__ void k_cvt_hs(const float* __restrict__ hs, unsigned short* __restrict__ hb) {
  int idx = blockIdx.x * blockDim.x + threadIdx.x;
  float4 v = ((const float4*)hs)[idx];
  ushort4 o;
  o.x = f2bf(v.x); o.y = f2bf(v.y); o.z = f2bf(v.z); o.w = f2bf(v.w);
  ((ushort4*)hb)[idx] = o;
}

// ---------------------------------------------------------------------------
// T4: out[t][h] = sum_e r[t,e] * down_bias[e][h]
__global__ void k_bias_out(const float* __restrict__ rw, const float* __restrict__ db,
                           float* __restrict__ out) {
  int idx = blockIdx.x * blockDim.x + threadIdx.x;
  int t = idx >> 10, h = idx & 1023;
  const float* r = rw + t * E_;
  float acc = 0.f;
#pragma unroll
  for (int e = 0; e < E_; ++e) acc += r[e] * db[(e << 10) + h];
  out[idx] = acc;
}

// ---------------------------------------------------------------------------
// GEMM1: 256x256 tile (256 tokens x 256 B-rows = 128 d), BK=64, 512 threads,
//        8 waves 2Mx4N, per-wave 128x64, acc[8][4]. (validated round 5)
//   Pipeline: STAGE(t+1); vmcnt(8); barrier; compute(t); barrier.
// grid (8, 8, 16), 512 threads
__global__ void __launch_bounds__(512, 2)
k_gemm1(const unsigned short* __restrict__ hb,
        const unsigned short* __restrict__ wg,
        const unsigned short* __restrict__ wu,
        const float* __restrict__ gub,
        const float* __restrict__ rw,
        unsigned short* __restrict__ act) {
  __shared__ __align__(16) short lsA[2][256 * 64];
  __shared__ __align__(16) short lsB[2][256 * 64];
  const int e     = blockIdx.z;
  const int t0    = blockIdx.y * 256;
  const int d0blk = blockIdx.x * 128;
  const int tid  = threadIdx.x;
  const int lane = tid & 63;
  const int w    = tid >> 6;
  const int wm = w >> 2, wn = w & 3;
  const int lo = lane & 15, hi = lane >> 4;

  const unsigned short* aS[4];
  const unsigned short* bS[4];
  int ldst[4];
#pragma unroll
  for (int i = 0; i < 4; ++i) {
    int lin = tid + i * 512;            // 0..2047
    int row = lin >> 3, ch = lin & 7;
    int sch = ch ^ (row & 7);           // source pre-swizzle (dest stays linear)
    ldst[i] = lin * 8;
    aS[i] = hb + (size_t)(t0 + row) * H_ + sch * 8;
    int dl = ((row >> 5) << 4) + (row & 15);
    const unsigned short* bp = ((row >> 4) & 1) ? wu : wg;
    bS[i] = bp + (((size_t)e << 10) + d0blk + dl) * H_ + sch * 8;
  }

#define G1_STAGE(buf, k0)                                                      \
  {                                                                            \
    _Pragma("unroll")                                                          \
    for (int i = 0; i < 4; ++i) gload16(aS[i] + (k0), &lsA[buf][ldst[i]]);     \
    _Pragma("unroll")                                                          \
    for (int i = 0; i < 4; ++i) gload16(bS[i] + (k0), &lsB[buf][ldst[i]]);     \
  }

  f32x4 acc[8][4];
#pragma unroll
  for (int mi = 0; mi < 8; ++mi)
#pragma unroll
    for (int nf = 0; nf < 4; ++nf) acc[mi][nf] = (f32x4)0.f;

  const int cb0 = ((0 | hi) ^ (lo & 7)) << 3;
  const int cb1 = ((4 | hi) ^ (lo & 7)) << 3;
  const int arow = (wm * 128 + lo) * 64;
  const int brow = (wn * 64 + lo) * 64;

#define G_COMPUTE(LA, LB)                                                      \
  {                                                                            \
    bf16x8 bfr[4], af[4];                                                      \
    _Pragma("unroll")                                                          \
    for (int nf = 0; nf < 4; ++nf) bfr[nf] = *(const bf16x8*)&LB[brow + nf * 1024 + cb0]; \
    _Pragma("unroll")                                                          \
    for (int mi = 0; mi < 4; ++mi) af[mi] = *(const bf16x8*)&LA[arow + mi * 1024 + cb0];  \
    __builtin_amdgcn_s_setprio(1);                                             \
    _Pragma("unroll")                                                          \
    for (int mi = 0; mi < 4; ++mi)                                             \
      _Pragma("unroll")                                                        \
      for (int nf = 0; nf < 4; ++nf)                                           \
        acc[mi][nf] = __builtin_amdgcn_mfma_f32_16x16x32_bf16(af[mi], bfr[nf], acc[mi][nf], 0, 0, 0); \
    __builtin_amdgcn_s_setprio(0);                                             \
    _Pragma("unroll")                                                          \
    for (int mi = 0; mi < 4; ++mi) af[mi] = *(const bf16x8*)&LA[arow + (mi + 4) * 1024 + cb0]; \
    __builtin_amdgcn_s_setprio(1);                                             \
    _Pragma("unroll")                                                          \
    for (int mi = 0; mi < 4; ++mi)                                             \
      _Pragma("unroll")                                                        \
      for (int nf = 0; nf < 4; ++nf)                                           \
        acc[mi + 4][nf] = __builtin_amdgcn_mfma_f32_16x16x32_bf16(af[mi], bfr[nf], acc[mi + 4][nf], 0, 0, 0); \
    __builtin_amdgcn_s_setprio(0);                                             \
    _Pragma("unroll")                                                          \
    for (int nf = 0; nf < 4; ++nf) bfr[nf] = *(const bf16x8*)&LB[brow + nf * 1024 + cb1]; \
    _Pragma("unroll")                                                          \
    for (int mi = 0; mi < 4; ++mi) af[mi] = *(const bf16x8*)&LA[arow + mi * 1024 + cb1];  \
    __builtin_amdgcn_s_setprio(1);                                             \
    _Pragma("unroll")                                                          \
    for (int mi = 0; mi < 4; ++mi)                                             \
      _Pragma("unroll")                                                        \
      for (int nf = 0; nf < 4; ++nf)                                           \
        acc[mi][nf] = __builtin_amdgcn_mfma_f32_16x16x32_bf16(af[mi], bfr[nf], acc[mi][nf], 0, 0, 0); \
    __builtin_amdgcn_s_setprio(0);                                             \
    _Pragma("unroll")                                                          \
    for (int mi = 0; mi < 4; ++mi) af[mi] = *(const bf16x8*)&LA[arow + (mi + 4) * 1024 + cb1]; \
    __builtin_amdgcn_s_setprio(1);                                             \
    _Pragma("unroll")                                                          \
    for (int mi = 0; mi < 4; ++mi)                                             \
      _Pragma("unroll")                                                        \
      for (int nf = 0; nf < 4; ++nf)                                           \
        acc[mi + 4][nf] = __builtin_amdgcn_mfma_f32_16x16x32_bf16(af[mi], bfr[nf], acc[mi + 4][nf], 0, 0, 0); \
    __builtin_amdgcn_s_setprio(0);                                             \
  }

  G1_STAGE(0, 0);
  for (int kt = 0; kt < 15; ++kt) {
    const int cur = kt & 1;
    G1_STAGE(cur ^ 1, (kt + 1) * 64);
    asm volatile("s_waitcnt vmcnt(8)\n\ts_barrier" ::: "memory");
    if (cur == 0) G_COMPUTE(lsA[0], lsB[0]) else G_COMPUTE(lsA[1], lsB[1]);
    asm volatile("s_barrier" ::: "memory");
  }
  asm volatile("s_waitcnt vmcnt(0)\n\ts_barrier" ::: "memory");
  G_COMPUTE(lsA[1], lsB[1]);
#undef G1_STAGE

  // epilogue: bias + clips + glu + routing scale -> act bf16
  float gb[2], ub[2];
#pragma unroll
  for (int j = 0; j < 2; ++j) {
    const int d = d0blk + (wn * 2 + j) * 16 + lo;
    gb[j] = gub[e * TWO_D + 2 * d];
    ub[j] = gub[e * TWO_D + 2 * d + 1];
  }
#pragma unroll
  for (int mi = 0; mi < 8; ++mi) {
#pragma unroll
    for (int rr = 0; rr < 4; ++rr) {
      const int t = t0 + wm * 128 + mi * 16 + hi * 4 + rr;
      const float r = rw[t * E_ + e];
#pragma unroll
      for (int j = 0; j < 2; ++j) {
        const int d = d0blk + (wn * 2 + j) * 16 + lo;
        float g = acc[mi][2 * j][rr]     + gb[j];
        float u = acc[mi][2 * j + 1][rr] + ub[j];
        g = fminf(g, 7.0f);
        u = fminf(fmaxf(u, -7.0f), 7.0f);
        float glu = g / (1.0f + __expf(-1.702f * g));
        act[(size_t)t * KFLAT + (e << 10) + d] = f2bf((u + 1.0f) * glu * r);
      }
    }
  }
}

// ---------------------------------------------------------------------------
// GEMM2: out[T][H] += act[T][E*D] @ Wd^T[H][E*D]^T — same 256x256 8-wave
//   counted-vmcnt structure as gemm1. split-K=8 (grid 4x8x8 = 256 blocks),
//   K-chunk 2048 = 32 BK-iters. f32 atomics on top of bias-initialized out.
__global__ void __launch_bounds__(512, 2)
k_gemm2(const unsigned short* __restrict__ act,
        const unsigned short* __restrict__ wd,
        float* __restrict__ out) {
  __shared__ __align__(16) short lsA[2][256 * 64];
  __shared__ __align__(16) short lsB[2][256 * 64];
  const int t0   = blockIdx.y * 256;
  const int h0   = blockIdx.x * 256;
  const int kbeg = blockIdx.z * (KFLAT / 8);
  const int tid  = threadIdx.x;
  const int lane = tid & 63;
  const int w    = tid >> 6;
  const int wm = w >> 2, wn = w & 3;
  const int lo = lane & 15, hi = lane >> 4;

  const unsigned short* aS[4];
  const unsigned short* bS[4];
  int ldst[4];
#pragma unroll
  for (int i = 0; i < 4; ++i) {
    int lin = tid + i * 512;
    int row = lin >> 3, ch = lin & 7;
    int sch = ch ^ (row & 7);
    ldst[i] = lin * 8;
    aS[i] = act + (size_t)(t0 + row) * KFLAT + kbeg + sch * 8;
    bS[i] = wd  + (size_t)(h0 + row) * KFLAT + kbeg + sch * 8;
  }

#define G2_STAGE(buf, k0)                                                      \
  {                                                                            \
    _Pragma("unroll")                                                          \
    for (int i = 0; i < 4; ++i) gload16(aS[i] + (k0), &lsA[buf][ldst[i]]);     \
    _Pragma("unroll")                                                          \
    for (int i = 0; i < 4; ++i) gload16(bS[i] + (k0), &lsB[buf][ldst[i]]);     \
  }

  f32x4 acc[8][4];
#pragma unroll
  for (int mi = 0; mi < 8; ++mi)
#pragma unroll
    for (int nf = 0; nf < 4; ++nf) acc[mi][nf] = (f32x4)0.f;

  const int cb0 = ((0 | hi) ^ (lo & 7)) << 3;
  const int cb1 = ((4 | hi) ^ (lo & 7)) << 3;
  const int arow = (wm * 128 + lo) * 64;
  const int brow = (wn * 64 + lo) * 64;

  G2_STAGE(0, 0);
  for (int kt = 0; kt < 31; ++kt) {
    const int cur = kt & 1;
    G2_STAGE(cur ^ 1, (kt + 1) * 64);
    asm volatile("s_waitcnt vmcnt(8)\n\ts_barrier" ::: "memory");
    if (cur == 0) G_COMPUTE(lsA[0], lsB[0]) else G_COMPUTE(lsA[1], lsB[1]);
    asm volatile("s_barrier" ::: "memory");
  }
  asm volatile("s_waitcnt vmcnt(0)\n\ts_barrier" ::: "memory");
  G_COMPUTE(lsA[1], lsB[1]);
#undef G2_STAGE

#pragma unroll
  for (int mi = 0; mi < 8; ++mi) {
#pragma unroll
    for (int rr = 0; rr < 4; ++rr) {
      const int t = t0 + wm * 128 + mi * 16 + hi * 4 + rr;
#pragma unroll
      for (int nf = 0; nf < 4; ++nf) {
        const int h = h0 + wn * 64 + nf * 16 + lo;
        atomicAdd(&out[(size_t)t * H_ + h], acc[mi][nf][rr]);
      }
    }
  }
}

// ---------------------------------------------------------------------------
extern "C" void kernel_launch(void* const* d_in, const int* in_sizes, int n_in,
                              void* d_out, int out_size, void* d_ws, size_t ws_size,
                              hipStream_t stream) {
  const float* hs  = (const float*)d_in[0];   // [1,2048,1024]
  const float* rw  = (const float*)d_in[1];   // [2048,16]
  const float* gup = (const float*)d_in[2];   // [16,1024,2048]
  const float* gub = (const float*)d_in[3];   // [16,2048]
  const float* dnp = (const float*)d_in[4];   // [16,1024,1024]
  const float* dnb = (const float*)d_in[5];   // [16,1024]
  float* out = (float*)d_out;                 // [2048*1024] f32

  // workspace layout (bytes): hb 4MB | wg 32MB | wu 32MB | wd 32MB | act 64MB
  char* ws = (char*)d_ws;
  unsigned short* hb  = (unsigned short*)(ws);
  unsigned short* wg  = (unsigned short*)(ws + (4UL   << 20));
  unsigned short* wu  = (unsigned short*)(ws + (36UL  << 20));
  unsigned short* wd  = (unsigned short*)(ws + (68UL  << 20));
  unsigned short* act = (unsigned short*)(ws + (100UL << 20));

  k_cvt_hs  <<<(T_ * H_ / 4) / 256, 256, 0, stream>>>(hs, hb);
  k_trans_gu<<<dim3(TWO_D / 128, H_ / 64, E_), 256, 0, stream>>>(gup, wg, wu);
  k_trans_dn<<<dim3(H_ / 64, D_ / 128, E_),    256, 0, stream>>>(dnp, wd);
  k_bias_out<<<(T_ * H_) / 256, 256, 0, stream>>>(rw, dnb, out);
  k_gemm1   <<<dim3(TWO_D / 256, T_ / 256, E_), 512, 0, stream>>>(hb, wg, wu, gub, rw, act);
  k_gemm2   <<<dim3(H_ / 256, T_ / 256, 8),     512, 0, stream>>>(act, wd, out);
}